// Round 8
// baseline (161.515 us; speedup 1.0000x reference)
//
#include <hip/hip_runtime.h>
#include <hip/hip_bf16.h>

// MSEL_Feat: persistent pipelined partial-sum kernel + tiny epilogue.
//   N=8192, D=2048, num_pos=4, id_num=2048.
//   Per identity, 25 scalars: rr[p],ii[p],sr[p],si[p],ri[p],rt[p],tt
//   (S=sum_p r_p, T=sum_p ir_p; loo_ir==loo_rgb per reference bug).
//
// R2-R6 ledger: four structures all pinned at ~46us / 2.75 TB/s aggregate
// reads. All were ONE-SHOT: issue-all -> vmcnt(0) -> compute -> retire.
// This round: continuous-issue pipeline (copy-bench style). 512 blocks
// (2/CU resident), 4 identities per block, register double-buffer,
// counted vmcnt(16) (issue next gen BEFORE waiting current gen; never
// drain to 0 mid-loop). No __syncthreads in the loop (compiler would
// emit vmcnt(0) before s_barrier and kill the pipeline): per-wave lane-0
// atomicAdds 25 partials into zeroed ws[25][id_num].

typedef float f32x4 __attribute__((ext_vector_type(4)));

constexpr int D    = 2048;
constexpr int NPOS = 4;
constexpr int TPB  = 256;
constexpr int NACC = 25;
constexpr int IDS  = 4;      // identities per block

__global__ void zero_out_kernel(float* out) { out[0] = 0.0f; }

__global__ void __launch_bounds__(TPB, 2) msel_partial_kernel(
        const float* __restrict__ in1,   // RGB feats [N, D]
        const float* __restrict__ in2,   // IR  feats [N, D]
        float* __restrict__ ws,          // [NACC][id_num], pre-zeroed
        int id_num) {
    const long id0 = (long)blockIdx.x * IDS;
    const float* a_base = in1 + id0 * (long)(NPOS * D);
    const float* b_base = in2 + id0 * (long)(NPOS * D);

    // per-thread byte offsets within one identity's 32KB block
    unsigned ofs[8];
#pragma unroll
    for (int p = 0; p < NPOS; ++p)
#pragma unroll
        for (int h = 0; h < 2; ++h)
            ofs[p * 2 + h] = (unsigned)(p * (D * 4) + h * 4096 + threadIdx.x * 16);

    f32x4 A0[8], B0[8], A1[8], B1[8];   // double-buffered generations

    auto issue = [&](f32x4 (&A)[8], f32x4 (&B)[8], int k) {
        const float* ra = a_base + (long)k * (NPOS * D);
        const float* rb = b_base + (long)k * (NPOS * D);
#pragma unroll
        for (int j = 0; j < 8; ++j)
            asm volatile("global_load_dwordx4 %0, %1, %2"
                         : "=v"(A[j]) : "v"(ofs[j]), "s"(ra));
#pragma unroll
        for (int j = 0; j < 8; ++j)
            asm volatile("global_load_dwordx4 %0, %1, %2"
                         : "=v"(B[j]) : "v"(ofs[j]), "s"(rb));
    };

#define MSEL_WAIT(cnt, A, B)                                                   \
    asm volatile("s_waitcnt vmcnt(" #cnt ")"                                   \
                 : "+v"(A[0]), "+v"(A[1]), "+v"(A[2]), "+v"(A[3]),             \
                   "+v"(A[4]), "+v"(A[5]), "+v"(A[6]), "+v"(A[7]),             \
                   "+v"(B[0]), "+v"(B[1]), "+v"(B[2]), "+v"(B[3]),             \
                   "+v"(B[4]), "+v"(B[5]), "+v"(B[6]), "+v"(B[7]));            \
    __builtin_amdgcn_sched_barrier(0)

    auto process = [&](const f32x4 (&A)[8], const f32x4 (&B)[8], long id) {
        float acc[NACC];
#pragma unroll
        for (int k = 0; k < NACC; ++k) acc[k] = 0.0f;
#pragma unroll
        for (int h = 0; h < 2; ++h) {
#pragma unroll
            for (int e = 0; e < 4; ++e) {
                const float x0 = A[0 * 2 + h][e], x1 = A[1 * 2 + h][e],
                            x2 = A[2 * 2 + h][e], x3 = A[3 * 2 + h][e];
                const float y0 = B[0 * 2 + h][e], y1 = B[1 * 2 + h][e],
                            y2 = B[2 * 2 + h][e], y3 = B[3 * 2 + h][e];
                const float s = x0 + x1 + x2 + x3;
                const float t = y0 + y1 + y2 + y3;
                const float x[NPOS] = {x0, x1, x2, x3};
                const float y[NPOS] = {y0, y1, y2, y3};
                acc[24] = fmaf(t, t, acc[24]);                    // |T|^2
#pragma unroll
                for (int p = 0; p < NPOS; ++p) {
                    acc[0  + p] = fmaf(x[p], x[p], acc[0  + p]);  // rr
                    acc[4  + p] = fmaf(y[p], y[p], acc[4  + p]);  // ii
                    acc[8  + p] = fmaf(s,    x[p], acc[8  + p]);  // sr
                    acc[12 + p] = fmaf(s,    y[p], acc[12 + p]);  // si
                    acc[16 + p] = fmaf(x[p], y[p], acc[16 + p]);  // ri
                    acc[20 + p] = fmaf(x[p], t,    acc[20 + p]);  // rt
                }
            }
        }
        // 64-lane wave reduce; lane 0 adds the wave's partial
#pragma unroll
        for (int k = 0; k < NACC; ++k) {
            float v = acc[k];
#pragma unroll
            for (int off = 32; off > 0; off >>= 1) v += __shfl_down(v, off, 64);
            acc[k] = v;
        }
        if ((threadIdx.x & 63) == 0) {
#pragma unroll
            for (int k = 0; k < NACC; ++k)
                atomicAdd(ws + (long)k * id_num + id, acc[k]);
        }
    };

    // ---- software pipeline over 4 identities, never drain mid-loop ----
    issue(A0, B0, 0);
    issue(A1, B1, 1);
    MSEL_WAIT(16, A0, B0);            // gen0 ready (gen1 still in flight)
    process(A0, B0, id0 + 0);
    issue(A0, B0, 2);
    MSEL_WAIT(16, A1, B1);            // gen1 ready (gen2 in flight)
    process(A1, B1, id0 + 1);
    issue(A1, B1, 3);
    MSEL_WAIT(16, A0, B0);            // gen2 ready (gen3 in flight)
    process(A0, B0, id0 + 2);
    MSEL_WAIT(0, A1, B1);             // final drain
    process(A1, B1, id0 + 3);
#undef MSEL_WAIT
}

__global__ void __launch_bounds__(TPB) msel_epilogue_kernel(
        const float* __restrict__ ws, float* __restrict__ out, int id_num) {
    const int id = blockIdx.x * TPB + threadIdx.x;
    float contrib = 0.0f;
    if (id < id_num) {
        float tot[NACC];
#pragma unroll
        for (int k = 0; k < NACC; ++k) tot[k] = ws[(long)k * id_num + id];

        const float ss = tot[8] + tot[9] + tot[10] + tot[11];  // |S|^2
        const float tt = tot[24];                              // |T|^2
#pragma unroll
        for (int p = 0; p < NPOS; ++p) {
            const float rr = tot[0 + p];
            const float ii = tot[4 + p];
            const float sr = tot[8 + p];
            const float si = tot[12 + p];
            const float ri = tot[16 + p];
            const float rt = tot[20 + p];

            const float b2loo = (ss - 2.0f * sr + rr) * (1.0f / 9.0f);
            const float sq_intra_rgb = rr + b2loo - 2.0f * ((sr - rr) * (1.0f / 3.0f));
            const float sq_intra_ir  = ii + b2loo - 2.0f * ((si - ri) * (1.0f / 3.0f));
            const float sq_cross_rgb = rr + tt * 0.0625f - 0.5f * rt;
            const float sq_cross_ir  = ii + ss * 0.0625f - 0.5f * si;

            const float d_ir_rgb = sqrtf(fmaxf(sq_intra_rgb, 1e-12f));
            const float d_ir_ir  = sqrtf(fmaxf(sq_intra_ir,  1e-12f));
            const float d_cr_rgb = sqrtf(fmaxf(sq_cross_rgb, 1e-12f));
            const float d_cr_ir  = sqrtf(fmaxf(sq_cross_ir,  1e-12f));

            const float e1 = d_cr_rgb - d_ir_rgb;
            const float e2 = d_cr_ir  - d_ir_ir;
            contrib += e1 * e1 + e2 * e2;
        }
        contrib *= (1.0f / 16384.0f);   // /N/2, N=8192
    }

#pragma unroll
    for (int off = 32; off > 0; off >>= 1) contrib += __shfl_down(contrib, off, 64);
    __shared__ float lds[TPB / 64];
    if ((threadIdx.x & 63) == 0) lds[threadIdx.x >> 6] = contrib;
    __syncthreads();
    if (threadIdx.x == 0)
        atomicAdd(out, lds[0] + lds[1] + lds[2] + lds[3]);
}

extern "C" void kernel_launch(void* const* d_in, const int* in_sizes, int n_in,
                              void* d_out, int out_size, void* d_ws, size_t ws_size,
                              hipStream_t stream) {
    const float* in1 = (const float*)d_in[0];
    const float* in2 = (const float*)d_in[1];
    float* out = (float*)d_out;
    float* ws  = (float*)d_ws;

    const int id_num = in_sizes[0] / (NPOS * D);   // 2048

    hipMemsetAsync(ws, 0, (size_t)NACC * id_num * sizeof(float), stream);
    zero_out_kernel<<<1, 1, 0, stream>>>(out);
    msel_partial_kernel<<<id_num / IDS, TPB, 0, stream>>>(in1, in2, ws, id_num);
    msel_epilogue_kernel<<<(id_num + TPB - 1) / TPB, TPB, 0, stream>>>(ws, out, id_num);
}

// Round 10
// 150.068 us; speedup vs baseline: 1.0763x; 1.0763x over previous
//
#include <hip/hip_runtime.h>
#include <hip/hip_bf16.h>

// MSEL_Feat R9: test the LAST untested load path — DMA-to-LDS staging.
//   R2-R8 ledger: five structures (one-shot burst, 2x oversubscribe,
//   hoisted loads, forced-asm 16-deep MLP, counted-vmcnt pipeline) ALL
//   pinned at ~46-55us = 2.9 TB/s aggregate reads = 4.75 B/cyc/CU, vs
//   m13 copy read-side ~5.1 B/cyc/CU. Model: per-CU outstanding-request
//   queue x loaded latency caps the read service rate; software MLP is
//   irrelevant once the queue is full. global_load_lds uses a different
//   return path (no VGPR writeback) — if its outstanding budget differs,
//   this moves; otherwise ROOFLINE is established.
//
//   Math (verified absmax 0.0 in R2-R8): per identity 25 scalars
//   rr[p],ii[p],sr[p],si[p],ri[p],rt[p],tt from S=sum_p r_p, T=sum_p ir_p;
//   loo_ir==loo_rgb faithful to reference bug.

typedef float f32x4 __attribute__((ext_vector_type(4)));

constexpr int D    = 2048;
constexpr int NPOS = 4;
constexpr int TPB  = 256;
constexpr int NACC = 25;

__global__ void zero_out_kernel(float* out) { out[0] = 0.0f; }

__device__ __forceinline__ void gld_lds16(const void* g, void* l) {
    // width=16 DMA: LDS dst is wave-uniform base, HW adds lane*16.
    __builtin_amdgcn_global_load_lds(
        (const __attribute__((address_space(1))) uint32_t*)(uintptr_t)g,
        (__attribute__((address_space(3))) uint32_t*)(uint32_t)(uintptr_t)l,
        16, 0, 0);
}

__global__ void __launch_bounds__(TPB) msel_feat_kernel(
        const float* __restrict__ in1,   // RGB feats [N, D]
        const float* __restrict__ in2,   // IR  feats [N, D]
        float* __restrict__ out) {
    // 64 KB staging: chunk c (1KB) = arr*32 + p*8 + kb  (arr: in1/in2,
    // p: row, kb: KB-within-8KB-row). smem[c*1024 + lane*16].
    __shared__ __align__(16) unsigned char smem[64 * 1024];
    __shared__ float red[TPB / 64][NACC];

    const long id = blockIdx.x;
    const int  w  = threadIdx.x >> 6;     // wave 0..3
    const int  l  = threadIdx.x & 63;     // lane
    const float* base[2] = { in1 + id * (long)(NPOS * D),
                             in2 + id * (long)(NPOS * D) };

    // ---- stage: wave w issues 16 back-to-back global_load_lds (c=w*16+j)
#pragma unroll
    for (int j = 0; j < 16; ++j) {
        const int c   = w * 16 + j;
        const int arr = c >> 5;
        const int p   = (c >> 3) & 3;
        const int kb  = c & 7;
        gld_lds16(base[arr] + p * D + kb * 256 + l * 4,   // +l*16 bytes
                  &smem[c * 1024]);
    }
    asm volatile("s_waitcnt vmcnt(0)" ::: "memory");
    __syncthreads();

    // ---- compute: thread t reads chunk (arr*32+p*8+h*4+w), bytes l*16
    float acc[NACC];
#pragma unroll
    for (int k = 0; k < NACC; ++k) acc[k] = 0.0f;

#pragma unroll
    for (int h = 0; h < 2; ++h) {
        f32x4 rv[NPOS], iv[NPOS];
#pragma unroll
        for (int p = 0; p < NPOS; ++p) {
            rv[p] = *reinterpret_cast<const f32x4*>(
                        &smem[(0 * 32 + p * 8 + h * 4 + w) * 1024 + l * 16]);
            iv[p] = *reinterpret_cast<const f32x4*>(
                        &smem[(1 * 32 + p * 8 + h * 4 + w) * 1024 + l * 16]);
        }
#pragma unroll
        for (int e = 0; e < 4; ++e) {
            const float x0 = rv[0][e], x1 = rv[1][e], x2 = rv[2][e], x3 = rv[3][e];
            const float y0 = iv[0][e], y1 = iv[1][e], y2 = iv[2][e], y3 = iv[3][e];
            const float s = x0 + x1 + x2 + x3;
            const float t = y0 + y1 + y2 + y3;
            const float x[NPOS] = {x0, x1, x2, x3};
            const float y[NPOS] = {y0, y1, y2, y3};
            acc[24] = fmaf(t, t, acc[24]);                    // |T|^2
#pragma unroll
            for (int p = 0; p < NPOS; ++p) {
                acc[0  + p] = fmaf(x[p], x[p], acc[0  + p]);  // rr
                acc[4  + p] = fmaf(y[p], y[p], acc[4  + p]);  // ii
                acc[8  + p] = fmaf(s,    x[p], acc[8  + p]);  // sr
                acc[12 + p] = fmaf(s,    y[p], acc[12 + p]);  // si
                acc[16 + p] = fmaf(x[p], y[p], acc[16 + p]);  // ri
                acc[20 + p] = fmaf(x[p], t,    acc[20 + p]);  // rt
            }
        }
    }

    // ---- 64-lane wave reduce each accumulator ----
#pragma unroll
    for (int k = 0; k < NACC; ++k) {
        float v = acc[k];
#pragma unroll
        for (int off = 32; off > 0; off >>= 1) v += __shfl_down(v, off, 64);
        acc[k] = v;
    }
    if (l == 0) {
#pragma unroll
        for (int k = 0; k < NACC; ++k) red[w][k] = acc[k];
    }
    __syncthreads();

    if (threadIdx.x == 0) {
        float tot[NACC];
#pragma unroll
        for (int k = 0; k < NACC; ++k)
            tot[k] = red[0][k] + red[1][k] + red[2][k] + red[3][k];

        const float ss = tot[8] + tot[9] + tot[10] + tot[11];  // |S|^2
        const float tt = tot[24];                              // |T|^2
        float contrib = 0.0f;
#pragma unroll
        for (int p = 0; p < NPOS; ++p) {
            const float rr = tot[0 + p];
            const float ii = tot[4 + p];
            const float sr = tot[8 + p];
            const float si = tot[12 + p];
            const float ri = tot[16 + p];
            const float rt = tot[20 + p];

            const float b2loo = (ss - 2.0f * sr + rr) * (1.0f / 9.0f);
            const float sq_intra_rgb = rr + b2loo - 2.0f * ((sr - rr) * (1.0f / 3.0f));
            const float sq_intra_ir  = ii + b2loo - 2.0f * ((si - ri) * (1.0f / 3.0f));
            const float sq_cross_rgb = rr + tt * 0.0625f - 0.5f * rt;
            const float sq_cross_ir  = ii + ss * 0.0625f - 0.5f * si;

            const float d_ir_rgb = sqrtf(fmaxf(sq_intra_rgb, 1e-12f));
            const float d_ir_ir  = sqrtf(fmaxf(sq_intra_ir,  1e-12f));
            const float d_cr_rgb = sqrtf(fmaxf(sq_cross_rgb, 1e-12f));
            const float d_cr_ir  = sqrtf(fmaxf(sq_cross_ir,  1e-12f));

            const float e1 = d_cr_rgb - d_ir_rgb;
            const float e2 = d_cr_ir  - d_ir_ir;
            contrib += e1 * e1 + e2 * e2;
        }
        // loss = sum / N / 2, N = 8192
        atomicAdd(out, contrib * (1.0f / 16384.0f));
    }
}

extern "C" void kernel_launch(void* const* d_in, const int* in_sizes, int n_in,
                              void* d_out, int out_size, void* d_ws, size_t ws_size,
                              hipStream_t stream) {
    const float* in1 = (const float*)d_in[0];
    const float* in2 = (const float*)d_in[1];
    float* out = (float*)d_out;

    const int id_num = in_sizes[0] / (NPOS * D);   // 2048

    zero_out_kernel<<<1, 1, 0, stream>>>(out);
    msel_feat_kernel<<<id_num, TPB, 0, stream>>>(in1, in2, out);
}